// Round 1
// baseline (195.000 us; speedup 1.0000x reference)
//
#include <hip/hip_runtime.h>
#include <hip/hip_bf16.h>

#define T_STEPS 64
#define N_SIDE 256
#define N2 (N_SIDE * N_SIDE)   // 65536
#define HID 32

__global__ __launch_bounds__(256) void mlpconv_fp32_kernel(
    const float* __restrict__ x,
    const float* __restrict__ W0, const float* __restrict__ b0,
    const float* __restrict__ W1, const float* __restrict__ b1,
    const float* __restrict__ W2, const float* __restrict__ b2,
    float* __restrict__ out)
{
    const int s = blockIdx.x * 256 + threadIdx.x;   // grid point
    const int t = blockIdx.y;                       // time step
    const float* xt = x + (size_t)t * N2;

    // Stencil gather, replicating the reference's exact wrap semantics:
    //  l  = x[(s-1)   mod n^2]   (numpy negative flat-index fallthrough)
    //  l2 = x[(s-256) mod n^2]
    //  c  = x[s]
    //  r  = x[rowbase + (j+1) mod 256]   (row-periodic!)
    //  r2 = x[(s+256) mod n^2]
    const int sl  = (s - 1)      & (N2 - 1);
    const int sl2 = (s - N_SIDE) & (N2 - 1);
    const int sr  = (s & ~(N_SIDE - 1)) | ((s + 1) & (N_SIDE - 1));
    const int sr2 = (s + N_SIDE) & (N2 - 1);

    float in0 = xt[sl];
    float in1 = xt[sl2];
    float in2 = xt[s];
    float in3 = xt[sr];
    float in4 = xt[sr2];

    // Layer 0: 5 -> 32, ELU. Weights are wave-uniform -> s_load/SGPR operands.
    float h0[HID];
    #pragma unroll
    for (int k = 0; k < HID; ++k) {
        float z = b0[k];
        z = fmaf(in0, W0[0 * HID + k], z);
        z = fmaf(in1, W0[1 * HID + k], z);
        z = fmaf(in2, W0[2 * HID + k], z);
        z = fmaf(in3, W0[3 * HID + k], z);
        z = fmaf(in4, W0[4 * HID + k], z);
        h0[k] = (z > 0.0f) ? z : (__expf(z) - 1.0f);
    }

    // Layer 1: 32 -> 32 accumulate (the 2048-FLOP/point hot loop).
    float z1[HID];
    #pragma unroll
    for (int j = 0; j < HID; ++j) z1[j] = b1[j];
    #pragma unroll
    for (int i = 0; i < HID; ++i) {
        const float a = h0[i];
        #pragma unroll
        for (int j = 0; j < HID; ++j) {
            z1[j] = fmaf(a, W1[i * HID + j], z1[j]);
        }
    }

    // Layer 2 fused into the ELU epilogue: out = b2 + sum_j elu(z1[j]) * W2[j]
    float acc = b2[0];
    #pragma unroll
    for (int j = 0; j < HID; ++j) {
        const float zj = z1[j];
        const float h  = (zj > 0.0f) ? zj : (__expf(zj) - 1.0f);
        acc = fmaf(h, W2[j], acc);
    }

    out[(size_t)t * N2 + s] = acc;
}

extern "C" void kernel_launch(void* const* d_in, const int* in_sizes, int n_in,
                              void* d_out, int out_size, void* d_ws, size_t ws_size,
                              hipStream_t stream) {
    const float* x  = (const float*)d_in[0];
    const float* W0 = (const float*)d_in[1];
    const float* b0 = (const float*)d_in[2];
    const float* W1 = (const float*)d_in[3];
    const float* b1 = (const float*)d_in[4];
    const float* W2 = (const float*)d_in[5];
    const float* b2 = (const float*)d_in[6];
    float* out = (float*)d_out;

    dim3 grid(N2 / 256, T_STEPS);
    dim3 block(256);
    mlpconv_fp32_kernel<<<grid, block, 0, stream>>>(x, W0, b0, W1, b1, W2, b2, out);
}

// Round 2
// 149.803 us; speedup vs baseline: 1.3017x; 1.3017x over previous
//
#include <hip/hip_runtime.h>
#include <hip/hip_bf16.h>

#define T_STEPS 64
#define NS 256
#define N2 (NS * NS)          // 65536
#define HID 32

typedef _Float16 half8 __attribute__((ext_vector_type(8)));
typedef float float4v __attribute__((ext_vector_type(4)));

#define TILES_TOTAL (T_STEPS * (N2 / 16))   // 262144 16-point tiles
#define TPW 16                               // tiles per wave
#define WAVES_PER_BLOCK 4
#define NBLOCKS (TILES_TOTAL / (TPW * WAVES_PER_BLOCK))  // 4096

__device__ __forceinline__ float elu(float z) {
    return (z > 0.0f) ? z : (__expf(z) - 1.0f);
}

__global__ __launch_bounds__(256) void mlpconv_mfma_kernel(
    const float* __restrict__ x,
    const float* __restrict__ W0, const float* __restrict__ b0,
    const float* __restrict__ W1, const float* __restrict__ b1,
    const float* __restrict__ W2, const float* __restrict__ b2,
    float* __restrict__ out)
{
    const int lane = threadIdx.x & 63;
    const int wid  = threadIdx.x >> 6;
    const int m    = lane & 15;   // point index within 16-point tile (B-frag col)
    const int kg   = lane >> 4;   // k-group: this lane covers channels 8*kg..8*kg+7

    // ---------- per-lane weight preload (amortized over TPW tiles) ----------
    // W0 columns for this lane's 8 channels (kept fp32 for the VALU FMAs)
    float w0c[5][8];
    #pragma unroll
    for (int c = 0; c < 5; ++c)
        #pragma unroll
        for (int i = 0; i < 8; ++i)
            w0c[c][i] = W0[c * HID + kg * 8 + i];
    float b0v[8];
    #pragma unroll
    for (int i = 0; i < 8; ++i) b0v[i] = b0[kg * 8 + i];

    // A-fragments = W1^T (so MFMA yields z1^T: channel-major per lane).
    // A layout (16x16x32): row = lane&15, k = 8*(lane>>4)+i.
    // a0 covers output channels n = 0..15 (rows of W1^T), a1 covers n = 16..31.
    half8 a0, a1;
    #pragma unroll
    for (int i = 0; i < 8; ++i) {
        a0[i] = (_Float16)W1[(kg * 8 + i) * HID + m];
        a1[i] = (_Float16)W1[(kg * 8 + i) * HID + 16 + m];
    }
    // C-init = b1 in the C/D layout: row n = 4*kg + r, col = m.
    float4v c0i, c1i;
    #pragma unroll
    for (int r = 0; r < 4; ++r) {
        c0i[r] = b1[kg * 4 + r];
        c1i[r] = b1[16 + kg * 4 + r];
    }
    // W2 entries matching this lane's held channels in the D layout.
    float w2a[4], w2b[4];
    #pragma unroll
    for (int r = 0; r < 4; ++r) {
        w2a[r] = W2[kg * 4 + r];
        w2b[r] = W2[16 + kg * 4 + r];
    }
    const float b2v = b2[0];

    const int gw = blockIdx.x * WAVES_PER_BLOCK + wid;   // global wave id
    const int g0 = gw * TPW;

    for (int l = 0; l < TPW; ++l) {
        const int g  = g0 + l;
        const int t  = g >> 12;            // tile / (65536/16)
        const int s0 = (g & 4095) << 4;    // base point of tile
        const int s  = s0 + m;
        const float* xt = x + ((size_t)t << 16);

        // Exact reference wrap semantics (validated in round 1):
        const int sl  = (s - 1)  & (N2 - 1);
        const int sl2 = (s - NS) & (N2 - 1);
        const int sr  = (s & ~(NS - 1)) | ((s + 1) & (NS - 1));  // row-periodic
        const int sr2 = (s + NS) & (N2 - 1);

        const float in0 = xt[sl];
        const float in1 = xt[sl2];
        const float in2 = xt[s];
        const float in3 = xt[sr];
        const float in4 = xt[sr2];

        // Layer 0 computed directly in MFMA B-fragment layout:
        // B layout (16x16x32): col = lane&15 (= point m), k = 8*kg + i.
        half8 hfrag;
        #pragma unroll
        for (int i = 0; i < 8; ++i) {
            float z = b0v[i];
            z = fmaf(in0, w0c[0][i], z);
            z = fmaf(in1, w0c[1][i], z);
            z = fmaf(in2, w0c[2][i], z);
            z = fmaf(in3, w0c[3][i], z);
            z = fmaf(in4, w0c[4][i], z);
            hfrag[i] = (_Float16)elu(z);
        }

        // Layer 1: z1^T[n][m] = sum_k W1^T[n][k] * h0[k][m] + b1[n]
        float4v d0 = __builtin_amdgcn_mfma_f32_16x16x32_f16(a0, hfrag, c0i, 0, 0, 0);
        float4v d1 = __builtin_amdgcn_mfma_f32_16x16x32_f16(a1, hfrag, c1i, 0, 0, 0);

        // Layer 2: out[m] = b2 + sum_n elu(z1[n][m]) * W2[n]
        // Each lane holds 8 channels of point-column m; reduce over kg groups.
        float part = 0.0f;
        #pragma unroll
        for (int r = 0; r < 4; ++r) {
            part = fmaf(elu(d0[r]), w2a[r], part);
            part = fmaf(elu(d1[r]), w2b[r], part);
        }
        part += __shfl_xor(part, 16, 64);
        part += __shfl_xor(part, 32, 64);

        if (kg == 0) {
            out[((size_t)t << 16) + s] = part + b2v;
        }
    }
}

extern "C" void kernel_launch(void* const* d_in, const int* in_sizes, int n_in,
                              void* d_out, int out_size, void* d_ws, size_t ws_size,
                              hipStream_t stream) {
    const float* x  = (const float*)d_in[0];
    const float* W0 = (const float*)d_in[1];
    const float* b0 = (const float*)d_in[2];
    const float* W1 = (const float*)d_in[3];
    const float* b1 = (const float*)d_in[4];
    const float* W2 = (const float*)d_in[5];
    const float* b2 = (const float*)d_in[6];
    float* out = (float*)d_out;

    mlpconv_mfma_kernel<<<dim3(NBLOCKS), dim3(256), 0, stream>>>(
        x, W0, b0, W1, b1, W2, b2, out);
}

// Round 3
// 137.560 us; speedup vs baseline: 1.4176x; 1.0890x over previous
//
#include <hip/hip_runtime.h>
#include <hip/hip_bf16.h>
#include <hip/hip_fp16.h>

#define T_STEPS 64
#define NS 256
#define N2 (NS * NS)          // 65536
#define HID 32

typedef _Float16 h2    __attribute__((ext_vector_type(2)));
typedef _Float16 half8 __attribute__((ext_vector_type(8)));
typedef float    float4v __attribute__((ext_vector_type(4)));

#define TPW 16                               // tiles per wave = one full 256-pt row
#define WAVES_PER_BLOCK 4
#define TILES_TOTAL (T_STEPS * (N2 / 16))    // 262144
#define NBLOCKS (TILES_TOTAL / (TPW * WAVES_PER_BLOCK))  // 4096

__device__ __forceinline__ float eluf(float z) {
    return (z > 0.0f) ? z : (__expf(z) - 1.0f);
}

__device__ __forceinline__ h2 splat2(float f) {
    _Float16 h = (_Float16)f;
    h2 r; r[0] = h; r[1] = h;
    return r;
}

// elu on a packed pair: max(z, exp2(min(z,0)*log2e) - 1)
__device__ __forceinline__ h2 elu2(h2 z) {
    h2 zero; zero[0] = (_Float16)0.f; zero[1] = (_Float16)0.f;
    h2 zm = __builtin_elementwise_min(z, zero);
    h2 e  = __builtin_elementwise_exp2(zm * (_Float16)1.442695041f);
    h2 em1 = e + (_Float16)(-1.0f);
    return __builtin_elementwise_max(z, em1);
}

struct Frags {
    h2 w0h[5][4];     // W0 cols for this lane's 8 channels, packed in pairs
    h2 b0h[4];
    half8 a0, a1;     // W1^T A-fragments (ch 0..15 / 16..31)
    float4v c0i, c1i; // b1 in C/D layout
    float w2a[4], w2b[4];
    float b2v;
};

__device__ __forceinline__ void tile_body(
    const Frags& F, float in0, float in1, float in2, float in3, float in4,
    int kg, float* __restrict__ outp)
{
    // Layer 0 in packed f16, directly in MFMA B-frag layout (k = 8*kg + i).
    h2 zw[4];
    #pragma unroll
    for (int w = 0; w < 4; ++w) zw[w] = F.b0h[w];
    {
        h2 p;
        p = splat2(in0);
        #pragma unroll
        for (int w = 0; w < 4; ++w) zw[w] = p * F.w0h[0][w] + zw[w];
        p = splat2(in1);
        #pragma unroll
        for (int w = 0; w < 4; ++w) zw[w] = p * F.w0h[1][w] + zw[w];
        p = splat2(in2);
        #pragma unroll
        for (int w = 0; w < 4; ++w) zw[w] = p * F.w0h[2][w] + zw[w];
        p = splat2(in3);
        #pragma unroll
        for (int w = 0; w < 4; ++w) zw[w] = p * F.w0h[3][w] + zw[w];
        p = splat2(in4);
        #pragma unroll
        for (int w = 0; w < 4; ++w) zw[w] = p * F.w0h[4][w] + zw[w];
    }
    half8 hf;
    #pragma unroll
    for (int w = 0; w < 4; ++w) {
        h2 hw = elu2(zw[w]);
        hf[2 * w]     = hw[0];
        hf[2 * w + 1] = hw[1];
    }

    // Layer 1: z1^T = W1^T @ h  (+ b1 via C-init)
    float4v d0 = __builtin_amdgcn_mfma_f32_16x16x32_f16(F.a0, hf, F.c0i, 0, 0, 0);
    float4v d1 = __builtin_amdgcn_mfma_f32_16x16x32_f16(F.a1, hf, F.c1i, 0, 0, 0);

    // Layer 2 epilogue (fp32): out = b2 + sum_n elu(z1[n]) * W2[n]
    float part = 0.0f;
    #pragma unroll
    for (int r = 0; r < 4; ++r) {
        part = fmaf(eluf(d0[r]), F.w2a[r], part);
        part = fmaf(eluf(d1[r]), F.w2b[r], part);
    }
    part += __shfl_xor(part, 16, 64);
    part += __shfl_xor(part, 32, 64);

    if (kg == 0) *outp = part + F.b2v;
}

__global__ __launch_bounds__(256, 4) void mlpconv_pk_mfma_kernel(
    const float* __restrict__ x,
    const float* __restrict__ W0, const float* __restrict__ b0,
    const float* __restrict__ W1, const float* __restrict__ b1,
    const float* __restrict__ W2, const float* __restrict__ b2,
    float* __restrict__ out)
{
    const int lane = threadIdx.x & 63;
    const int wid  = threadIdx.x >> 6;
    const int m    = lane & 15;   // point (B col) / channel row n (A row)
    const int kg   = lane >> 4;   // k-group

    Frags F;
    #pragma unroll
    for (int c = 0; c < 5; ++c)
        #pragma unroll
        for (int w = 0; w < 4; ++w) {
            F.w0h[c][w][0] = (_Float16)W0[c * HID + kg * 8 + 2 * w];
            F.w0h[c][w][1] = (_Float16)W0[c * HID + kg * 8 + 2 * w + 1];
        }
    #pragma unroll
    for (int w = 0; w < 4; ++w) {
        F.b0h[w][0] = (_Float16)b0[kg * 8 + 2 * w];
        F.b0h[w][1] = (_Float16)b0[kg * 8 + 2 * w + 1];
    }
    #pragma unroll
    for (int i = 0; i < 8; ++i) {
        F.a0[i] = (_Float16)W1[(kg * 8 + i) * HID + m];
        F.a1[i] = (_Float16)W1[(kg * 8 + i) * HID + 16 + m];
    }
    #pragma unroll
    for (int r = 0; r < 4; ++r) {
        F.c0i[r] = b1[kg * 4 + r];
        F.c1i[r] = b1[16 + kg * 4 + r];
        F.w2a[r] = W2[kg * 4 + r];
        F.w2b[r] = W2[16 + kg * 4 + r];
    }
    F.b2v = b2[0];

    const int gw    = blockIdx.x * WAVES_PER_BLOCK + wid;  // global wave id
    const int g0    = gw * TPW;
    const int t     = g0 >> 12;          // uniform across the wave's 16 tiles
    const int sbase = (g0 & 4095) << 4;  // multiple of 256 -> one full row
    const int i0    = sbase >> 8;        // grid row (wave-uniform)

    const float* xt   = x   + ((size_t)t << 16);
    float*       outt = out + ((size_t)t << 16);

    if (i0 != 0 && i0 != 255) {
        // Interior row: all wraps are plain +/-1, +/-256, except the single
        // row-periodic case at l==15, m==15 (j=255 -> j=0).
        #pragma unroll
        for (int l = 0; l < TPW; ++l) {
            const int s = sbase + 16 * l + m;
            const float in0 = xt[s - 1];
            const float in1 = xt[s - NS];
            const float in2 = xt[s];
            const float in3 = (l == 15 && m == 15) ? xt[s + 1 - NS] : xt[s + 1];
            const float in4 = xt[s + NS];
            tile_body(F, in0, in1, in2, in3, in4, kg, outt + s);
        }
    } else {
        // Boundary rows (i0 == 0 or 255): generic masked indices (validated).
        #pragma unroll
        for (int l = 0; l < TPW; ++l) {
            const int s   = sbase + 16 * l + m;
            const int sl  = (s - 1)  & (N2 - 1);
            const int sl2 = (s - NS) & (N2 - 1);
            const int sr  = (s & ~(NS - 1)) | ((s + 1) & (NS - 1));
            const int sr2 = (s + NS) & (N2 - 1);
            tile_body(F, xt[sl], xt[sl2], xt[s], xt[sr], xt[sr2], kg, outt + s);
        }
    }
}

extern "C" void kernel_launch(void* const* d_in, const int* in_sizes, int n_in,
                              void* d_out, int out_size, void* d_ws, size_t ws_size,
                              hipStream_t stream) {
    const float* x  = (const float*)d_in[0];
    const float* W0 = (const float*)d_in[1];
    const float* b0 = (const float*)d_in[2];
    const float* W1 = (const float*)d_in[3];
    const float* b1 = (const float*)d_in[4];
    const float* W2 = (const float*)d_in[5];
    const float* b2 = (const float*)d_in[6];
    float* out = (float*)d_out;

    mlpconv_pk_mfma_kernel<<<dim3(NBLOCKS), dim3(256), 0, stream>>>(
        x, W0, b0, W1, b1, W2, b2, out);
}